// Round 1
// baseline (958.625 us; speedup 1.0000x reference)
//
#include <hip/hip_runtime.h>
#include <math.h>

// GeneralConvNet: 3x GeneralConv + ELU, then linear->sigmoid.
// Restructured: per layer  out = ELU( Adj@(x@Wm) + x@Ws + Eagg@We + deg*(bm+be) + bs )
// Adj aggregation done via CSR-by-dst built once per call (no float atomics).

static __device__ __forceinline__ float elu_f(float v){ return v > 0.f ? v : expm1f(v); }

// ---------- CSR build ----------
__global__ void k_hist(const int* __restrict__ ei, int* __restrict__ cnt, int E){
  int i = blockIdx.x * 256 + threadIdx.x;
  if (i < E) atomicAdd(&cnt[ei[E + i]], 1);
}

__global__ void k_alloc(const int* __restrict__ cnt, int* __restrict__ row_start,
                        int* __restrict__ cursor, int* __restrict__ gcount, int N){
  int i = blockIdx.x * 256 + threadIdx.x;
  int lane = threadIdx.x & 63;
  int c = (i < N) ? cnt[i] : 0;
  int s = c;
  #pragma unroll
  for (int d = 1; d < 64; d <<= 1){
    int t = __shfl_up(s, d);
    if (lane >= d) s += t;
  }
  int total = __shfl(s, 63);
  int base = 0;
  if (lane == 63) base = atomicAdd(gcount, total);
  base = __shfl(base, 63);
  int start = base + s - c;   // exclusive within wave + global base
  if (i < N){ row_start[i] = start; cursor[i] = start; }
}

__global__ void k_fill(const int* __restrict__ ei, int* __restrict__ cursor,
                       int* __restrict__ srcs, int* __restrict__ eids, int E){
  int e = blockIdx.x * 256 + threadIdx.x;
  if (e < E){
    int d = ei[E + e];
    int pos = atomicAdd(&cursor[d], 1);
    srcs[pos] = ei[e];
    eids[pos] = e;
  }
}

// ---------- edge-attr aggregation (once, 16 lanes per node) ----------
__global__ void k_eagg(const float* __restrict__ eattr, const int* __restrict__ eids,
                       const int* __restrict__ row_start, const int* __restrict__ cnt,
                       float* __restrict__ Eagg, int N){
  int t = blockIdx.x * 256 + threadIdx.x;
  int i = t >> 4, k = t & 15;
  if (i >= N) return;
  int p0 = row_start[i], n = cnt[i];
  float s = 0.f;
  for (int p = 0; p < n; ++p) s += eattr[((long)eids[p0 + p] << 4) + k];
  Eagg[((long)i << 4) + k] = s;
}

// ---------- 64-dim feature aggregation: G[i] = sum_{e: dst=i} P[src(e)] ----------
__global__ void k_agg64(const float* __restrict__ P, const int* __restrict__ srcs,
                        const int* __restrict__ row_start, const int* __restrict__ cnt,
                        float* __restrict__ G, int N){
  int t = blockIdx.x * 256 + threadIdx.x;
  int i = t >> 6, c = t & 63;
  if (i >= N) return;
  int p0 = row_start[i], n = cnt[i];
  float s = 0.f;
  for (int p = 0; p < n; ++p) s += P[((long)srcs[p0 + p] << 6) + c];
  G[((long)i << 6) + c] = s;
}

// ---------- dense: out = [act]( A1@W1 + A2@W2 + addrow + deg*(bm+be) + bs ) ----------
// Tile 64 nodes x 64 outs, BK=16, 256 threads, 4x4 microtile per thread.
__global__ __launch_bounds__(256) void k_dense(
    const float* __restrict__ A1, const float* __restrict__ W1, int K1,
    const float* __restrict__ A2, const float* __restrict__ W2, int K2,
    const float* __restrict__ addrow,            // [N][64] or null
    const int*   __restrict__ cnt,               // null => no deg/bias epilogue
    const float* __restrict__ bm, const float* __restrict__ be, const float* __restrict__ bs,
    int act,
    float* __restrict__ outA,                    // [N][64]
    float* __restrict__ outB,                    // null or [N][65] concat region
    int N)
{
  __shared__ float As[64][20];   // pad to 20 floats: 16B-aligned float4 rows, mild conflict
  __shared__ float Bs[16][64];
  const int tid = threadIdx.x;
  const int tx = tid & 15, ty = tid >> 4;
  const int tile0 = blockIdx.x * 64;
  float acc[4][4] = {{0.f}};

  const float* Ap = A1; const float* Wp = W1; int K = K1;
  for (int pass = 0; pass < 2; ++pass){
    if (pass == 1){
      if (K2 == 0) break;
      Ap = A2; Wp = W2; K = K2;
    }
    for (int k0 = 0; k0 < K; k0 += 16){
      int ar = tid >> 2;
      int ac = (tid & 3) << 2;
      int gn = tile0 + ar;
      float4 av = make_float4(0.f, 0.f, 0.f, 0.f);
      if (gn < N) av = *reinterpret_cast<const float4*>(Ap + (long)gn * K + k0 + ac);
      *reinterpret_cast<float4*>(&As[ar][ac]) = av;
      int br = tid >> 4;
      int bc = (tid & 15) << 2;
      float4 bv = *reinterpret_cast<const float4*>(Wp + (long)(k0 + br) * 64 + bc);
      *reinterpret_cast<float4*>(&Bs[br][bc]) = bv;
      __syncthreads();
      #pragma unroll
      for (int kk = 0; kk < 16; ++kk){
        float a0 = As[4*ty+0][kk];
        float a1 = As[4*ty+1][kk];
        float a2 = As[4*ty+2][kk];
        float a3 = As[4*ty+3][kk];
        float4 b = *reinterpret_cast<const float4*>(&Bs[kk][tx << 2]);
        acc[0][0] += a0*b.x; acc[0][1] += a0*b.y; acc[0][2] += a0*b.z; acc[0][3] += a0*b.w;
        acc[1][0] += a1*b.x; acc[1][1] += a1*b.y; acc[1][2] += a1*b.z; acc[1][3] += a1*b.w;
        acc[2][0] += a2*b.x; acc[2][1] += a2*b.y; acc[2][2] += a2*b.z; acc[2][3] += a2*b.w;
        acc[3][0] += a3*b.x; acc[3][1] += a3*b.y; acc[3][2] += a3*b.z; acc[3][3] += a3*b.w;
      }
      __syncthreads();
    }
  }

  #pragma unroll
  for (int i = 0; i < 4; ++i){
    int node = tile0 + 4*ty + i;
    if (node >= N) continue;
    float degf = cnt ? (float)cnt[node] : 0.f;
    #pragma unroll
    for (int q = 0; q < 4; ++q){
      int j = (tx << 2) + q;
      float v = acc[i][q];
      if (addrow) v += addrow[((long)node << 6) + j];
      if (cnt)    v += degf * (bm[j] + be[j]) + bs[j];
      if (act)    v = elu_f(v);
      outA[((long)node << 6) + j] = v;
      if (outB) outB[(long)node * 65 + j] = v;
    }
  }
}

// ---------- final: logit = h3 @ Wl + bl; out0 = sigmoid; out2[:,64] = logit ----------
__global__ void k_final(const float* __restrict__ H, const float* __restrict__ Wl,
                        const float* __restrict__ bl,
                        float* __restrict__ out0, float* __restrict__ out2, int N){
  int t = blockIdx.x * 256 + threadIdx.x;
  int i = t >> 6, lane = t & 63;
  if (i >= N) return;
  float v = H[((long)i << 6) + lane] * Wl[lane];
  #pragma unroll
  for (int d = 32; d; d >>= 1) v += __shfl_xor(v, d);
  if (lane == 0){
    float logit = v + bl[0];
    out0[i] = 1.f / (1.f + expf(-logit));
    out2[(long)i * 65 + 64] = logit;
  }
}

extern "C" void kernel_launch(void* const* d_in, const int* in_sizes, int n_in,
                              void* d_out, int out_size, void* d_ws, size_t ws_size,
                              hipStream_t stream) {
  const int N = in_sizes[0] / 128;
  const int E = in_sizes[1] / 2;

  const float* x    = (const float*)d_in[0];
  const int*   ei   = (const int*)  d_in[1];
  const float* eat  = (const float*)d_in[2];
  const float* Wm1  = (const float*)d_in[3];  const float* bm1 = (const float*)d_in[4];
  const float* We1  = (const float*)d_in[5];  const float* be1 = (const float*)d_in[6];
  const float* Ws1  = (const float*)d_in[7];  const float* bs1 = (const float*)d_in[8];
  const float* Wm2  = (const float*)d_in[9];  const float* bm2 = (const float*)d_in[10];
  const float* We2  = (const float*)d_in[11]; const float* be2 = (const float*)d_in[12];
  const float* Ws2  = (const float*)d_in[13]; const float* bs2 = (const float*)d_in[14];
  const float* Wm3  = (const float*)d_in[15]; const float* bm3 = (const float*)d_in[16];
  const float* We3  = (const float*)d_in[17]; const float* be3 = (const float*)d_in[18];
  const float* Ws3  = (const float*)d_in[19]; const float* bs3 = (const float*)d_in[20];
  const float* Wl   = (const float*)d_in[21]; const float* bl  = (const float*)d_in[22];

  // workspace layout (4B elements)
  int*   wsi = (int*)d_ws;
  size_t o_cnt = 0;
  size_t o_gc  = o_cnt + (size_t)N;        // 64 ints
  size_t o_rs  = o_gc  + 64;
  size_t o_cur = o_rs  + (size_t)N;
  size_t o_src = o_cur + (size_t)N;
  size_t o_eid = o_src + (size_t)E;
  size_t o_eagg= o_eid + (size_t)E;        // float from here on
  size_t o_P   = o_eagg + (size_t)N * 16;
  size_t o_G   = o_P   + (size_t)N * 64;
  size_t o_H   = o_G   + (size_t)N * 64;   // total ~94 MB

  int* cnt       = wsi + o_cnt;
  int* gcount    = wsi + o_gc;
  int* row_start = wsi + o_rs;
  int* cursor    = wsi + o_cur;
  int* srcs      = wsi + o_src;
  int* eids      = wsi + o_eid;
  float* Eagg    = (float*)(wsi + o_eagg);
  float* P       = (float*)(wsi + o_P);
  float* G       = (float*)(wsi + o_G);
  float* H       = (float*)(wsi + o_H);

  float* out0     = (float*)d_out;                       // [N]
  float* out_feat = (float*)d_out + N;                   // [N][64]
  float* out_cat  = (float*)d_out + (size_t)N * 65;      // [N][65]

  const int gE  = (E + 255) / 256;
  const int gN  = (N + 255) / 256;
  const int g16 = ((size_t)N * 16 + 255) / 256;
  const int g64 = ((size_t)N * 64 + 255) / 256;
  const int gT  = (N + 63) / 64;

  hipMemsetAsync(cnt, 0, (size_t)(N + 64) * sizeof(int), stream);
  k_hist <<<gE, 256, 0, stream>>>(ei, cnt, E);
  k_alloc<<<gN, 256, 0, stream>>>(cnt, row_start, cursor, gcount, N);
  k_fill <<<gE, 256, 0, stream>>>(ei, cursor, srcs, eids, E);
  k_eagg <<<g16, 256, 0, stream>>>(eat, eids, row_start, cnt, Eagg, N);

  // ---- layer 1 (Cin=128) ----
  k_dense<<<gT, 256, 0, stream>>>(x, Wm1, 128, nullptr, nullptr, 0,
                                  nullptr, nullptr, nullptr, nullptr, nullptr, 0,
                                  P, nullptr, N);
  k_agg64<<<g64, 256, 0, stream>>>(P, srcs, row_start, cnt, G, N);
  k_dense<<<gT, 256, 0, stream>>>(x, Ws1, 128, Eagg, We1, 16,
                                  G, cnt, bm1, be1, bs1, 1,
                                  H, nullptr, N);
  // ---- layer 2 (Cin=64) ----
  k_dense<<<gT, 256, 0, stream>>>(H, Wm2, 64, nullptr, nullptr, 0,
                                  nullptr, nullptr, nullptr, nullptr, nullptr, 0,
                                  P, nullptr, N);
  k_agg64<<<g64, 256, 0, stream>>>(P, srcs, row_start, cnt, G, N);
  k_dense<<<gT, 256, 0, stream>>>(H, Ws2, 64, Eagg, We2, 16,
                                  G, cnt, bm2, be2, bs2, 1,
                                  out_feat, out_cat, N);
  // ---- layer 3 (Cin=64) ----
  k_dense<<<gT, 256, 0, stream>>>(out_feat, Wm3, 64, nullptr, nullptr, 0,
                                  nullptr, nullptr, nullptr, nullptr, nullptr, 0,
                                  P, nullptr, N);
  k_agg64<<<g64, 256, 0, stream>>>(P, srcs, row_start, cnt, G, N);
  k_dense<<<gT, 256, 0, stream>>>(out_feat, Ws3, 64, Eagg, We3, 16,
                                  G, cnt, bm3, be3, bs3, 1,
                                  H, nullptr, N);

  k_final<<<g64, 256, 0, stream>>>(H, Wl, bl, out0, out_cat, N);
}

// Round 2
// 703.609 us; speedup vs baseline: 1.3624x; 1.3624x over previous
//
#include <hip/hip_runtime.h>
#include <math.h>

// GeneralConvNet: 3x GeneralConv + ELU, then linear->sigmoid.
// per layer: out = ELU( Adj@(x@Wm) + x@Ws + Eagg@We + deg*(bm+be) + bs )
// CSR-by-dst built per call; P (=x@Wm) stored bf16 to halve gather traffic.

static __device__ __forceinline__ float elu_f(float v){ return v > 0.f ? v : expm1f(v); }

static __device__ __forceinline__ unsigned short f2bf_rne(float f){
  unsigned u = __float_as_uint(f);
  u += 0x7FFFu + ((u >> 16) & 1u);
  return (unsigned short)(u >> 16);
}
static __device__ __forceinline__ float bf2f(unsigned short b){
  return __uint_as_float(((unsigned)b) << 16);
}

// ---------- CSR build ----------
__global__ void k_hist(const int* __restrict__ ei, int* __restrict__ cnt, int E){
  int i = blockIdx.x * 256 + threadIdx.x;
  if (i < E) atomicAdd(&cnt[ei[E + i]], 1);
}

__global__ void k_alloc(const int* __restrict__ cnt, int* __restrict__ row_start,
                        int* __restrict__ cursor, int* __restrict__ gcount, int N){
  int i = blockIdx.x * 256 + threadIdx.x;
  int lane = threadIdx.x & 63;
  int c = (i < N) ? cnt[i] : 0;
  int s = c;
  #pragma unroll
  for (int d = 1; d < 64; d <<= 1){
    int t = __shfl_up(s, d);
    if (lane >= d) s += t;
  }
  int total = __shfl(s, 63);
  int base = 0;
  if (lane == 63) base = atomicAdd(gcount, total);
  base = __shfl(base, 63);
  int start = base + s - c;
  if (i < N){ row_start[i] = start; cursor[i] = start; }
}

__global__ void k_fill(const int* __restrict__ ei, int* __restrict__ cursor,
                       int2* __restrict__ adj, int E){
  int e = blockIdx.x * 256 + threadIdx.x;
  if (e < E){
    int d = ei[E + e];
    int pos = atomicAdd(&cursor[d], 1);
    adj[pos] = make_int2(ei[e], e);   // {src, edge_id}
  }
}

// ---------- edge-attr aggregation (once). 4 lanes per node, float4 channels ----------
__global__ void k_eagg(const float4* __restrict__ eattr4, const int2* __restrict__ adj,
                       const int* __restrict__ row_start, const int* __restrict__ cnt,
                       float4* __restrict__ Eagg4, int N){
  int t = blockIdx.x * 256 + threadIdx.x;
  int i = t >> 2, q = t & 3;
  if (i >= N) return;
  int lane = threadIdx.x & 63;
  int gbase = lane & 60;               // 4-lane group base
  int p0 = row_start[i], n = cnt[i];
  float4 s = make_float4(0.f, 0.f, 0.f, 0.f);
  for (int c = 0; c < n; c += 4){
    int m = n - c; if (m > 4) m = 4;
    int ereg = (q < m) ? adj[p0 + c + q].y : 0;
    for (int p = 0; p < m; ++p){
      int e = __shfl(ereg, gbase + p);
      float4 v = eattr4[(long)e * 4 + q];
      s.x += v.x; s.y += v.y; s.z += v.z; s.w += v.w;
    }
  }
  Eagg4[(long)i * 4 + q] = s;
}

// ---------- 64-dim bf16 gather-aggregate: G[i] = sum_{e: dst=i} P[src(e)] ----------
// 32 lanes per node, 2 channels (bf16x2 = 4B) per lane. srcs broadcast via shfl.
__global__ void k_agg64(const ushort2* __restrict__ P, const int2* __restrict__ adj,
                        const int* __restrict__ row_start, const int* __restrict__ cnt,
                        float2* __restrict__ G, int N){
  int t = blockIdx.x * 256 + threadIdx.x;
  int i = t >> 5, h = t & 31;
  if (i >= N) return;
  int lane = threadIdx.x & 63;
  int half = lane & 32;                // node-half base within wave
  int p0 = row_start[i], n = cnt[i];
  float s0 = 0.f, s1 = 0.f;
  for (int c = 0; c < n; c += 32){
    int m = n - c; if (m > 32) m = 32;
    int sreg = (h < m) ? adj[p0 + c + h].x : 0;
    for (int p = 0; p < m; ++p){
      int src = __shfl(sreg, half + p);
      ushort2 v = P[(long)src * 32 + h];
      s0 += bf2f(v.x); s1 += bf2f(v.y);
    }
  }
  G[(long)i * 32 + h] = make_float2(s0, s1);
}

// ---------- dense: out = [act]( A1@W1 + A2@W2 + addrow + deg*(bm+be) + bs ) ----------
// Tile 64 nodes x 64 outs, BK=16, 256 threads, 4x4 microtile.
__global__ __launch_bounds__(256) void k_dense(
    const float* __restrict__ A1, const float* __restrict__ W1, int K1,
    const float* __restrict__ A2, const float* __restrict__ W2, int K2,
    const float* __restrict__ addrow,            // [N][64] or null
    const int*   __restrict__ cnt,               // null => no deg/bias epilogue
    const float* __restrict__ bm, const float* __restrict__ be, const float* __restrict__ bs,
    int act, int out_bf16,
    float* __restrict__ outA,                    // [N][64] f32, or [N][64] bf16 if out_bf16
    float* __restrict__ outB,                    // null or [N][65] concat region
    int N)
{
  __shared__ float AsT[16][68];   // [kk][row]: inner-loop float4 reads are broadcast
  __shared__ float Bs[16][64];
  const int tid = threadIdx.x;
  const int tx = tid & 15, ty = tid >> 4;
  const int tile0 = blockIdx.x * 64;
  float acc[4][4] = {{0.f}};

  const float* Ap = A1; const float* Wp = W1; int K = K1;
  for (int pass = 0; pass < 2; ++pass){
    if (pass == 1){
      if (K2 == 0) break;
      Ap = A2; Wp = W2; K = K2;
    }
    for (int k0 = 0; k0 < K; k0 += 16){
      int ar = tid >> 2;              // row within tile 0..63
      int ac = (tid & 3) << 2;        // k-chunk 0..12
      int gn = tile0 + ar;
      float4 av = make_float4(0.f, 0.f, 0.f, 0.f);
      if (gn < N) av = *reinterpret_cast<const float4*>(Ap + (long)gn * K + k0 + ac);
      AsT[ac + 0][ar] = av.x;
      AsT[ac + 1][ar] = av.y;
      AsT[ac + 2][ar] = av.z;
      AsT[ac + 3][ar] = av.w;
      int br = tid >> 4;
      int bc = (tid & 15) << 2;
      float4 bv = *reinterpret_cast<const float4*>(Wp + (long)(k0 + br) * 64 + bc);
      *reinterpret_cast<float4*>(&Bs[br][bc]) = bv;
      __syncthreads();
      #pragma unroll
      for (int kk = 0; kk < 16; ++kk){
        float4 a = *reinterpret_cast<const float4*>(&AsT[kk][4 * ty]);
        float4 b = *reinterpret_cast<const float4*>(&Bs[kk][tx << 2]);
        acc[0][0] += a.x*b.x; acc[0][1] += a.x*b.y; acc[0][2] += a.x*b.z; acc[0][3] += a.x*b.w;
        acc[1][0] += a.y*b.x; acc[1][1] += a.y*b.y; acc[1][2] += a.y*b.z; acc[1][3] += a.y*b.w;
        acc[2][0] += a.z*b.x; acc[2][1] += a.z*b.y; acc[2][2] += a.z*b.z; acc[2][3] += a.z*b.w;
        acc[3][0] += a.w*b.x; acc[3][1] += a.w*b.y; acc[3][2] += a.w*b.z; acc[3][3] += a.w*b.w;
      }
      __syncthreads();
    }
  }

  #pragma unroll
  for (int i = 0; i < 4; ++i){
    int node = tile0 + 4*ty + i;
    if (node >= N) continue;
    float degf = cnt ? (float)cnt[node] : 0.f;
    float v[4];
    #pragma unroll
    for (int q = 0; q < 4; ++q) v[q] = acc[i][q];
    if (addrow){
      float4 ad = *reinterpret_cast<const float4*>(addrow + ((long)node << 6) + (tx << 2));
      v[0] += ad.x; v[1] += ad.y; v[2] += ad.z; v[3] += ad.w;
    }
    #pragma unroll
    for (int q = 0; q < 4; ++q){
      int j = (tx << 2) + q;
      if (cnt) v[q] += degf * (bm[j] + be[j]) + bs[j];
      if (act) v[q] = elu_f(v[q]);
    }
    if (out_bf16){
      ushort4 o;
      o.x = f2bf_rne(v[0]); o.y = f2bf_rne(v[1]); o.z = f2bf_rne(v[2]); o.w = f2bf_rne(v[3]);
      *reinterpret_cast<ushort4*>(reinterpret_cast<unsigned short*>(outA) + ((long)node << 6) + (tx << 2)) = o;
    } else {
      *reinterpret_cast<float4*>(outA + ((long)node << 6) + (tx << 2)) =
          make_float4(v[0], v[1], v[2], v[3]);
    }
    if (outB){
      #pragma unroll
      for (int q = 0; q < 4; ++q) outB[(long)node * 65 + (tx << 2) + q] = v[q];
    }
  }
}

// ---------- final: logit = h3 @ Wl + bl; out0 = sigmoid; out2[:,64] = logit ----------
__global__ void k_final(const float* __restrict__ H, const float* __restrict__ Wl,
                        const float* __restrict__ bl,
                        float* __restrict__ out0, float* __restrict__ out2, int N){
  int t = blockIdx.x * 256 + threadIdx.x;
  int i = t >> 6, lane = t & 63;
  if (i >= N) return;
  float v = H[((long)i << 6) + lane] * Wl[lane];
  #pragma unroll
  for (int d = 32; d; d >>= 1) v += __shfl_xor(v, d);
  if (lane == 0){
    float logit = v + bl[0];
    out0[i] = 1.f / (1.f + expf(-logit));
    out2[(long)i * 65 + 64] = logit;
  }
}

extern "C" void kernel_launch(void* const* d_in, const int* in_sizes, int n_in,
                              void* d_out, int out_size, void* d_ws, size_t ws_size,
                              hipStream_t stream) {
  const int N = in_sizes[0] / 128;
  const int E = in_sizes[1] / 2;

  const float* x    = (const float*)d_in[0];
  const int*   ei   = (const int*)  d_in[1];
  const float* eat  = (const float*)d_in[2];
  const float* Wm1  = (const float*)d_in[3];  const float* bm1 = (const float*)d_in[4];
  const float* We1  = (const float*)d_in[5];  const float* be1 = (const float*)d_in[6];
  const float* Ws1  = (const float*)d_in[7];  const float* bs1 = (const float*)d_in[8];
  const float* Wm2  = (const float*)d_in[9];  const float* bm2 = (const float*)d_in[10];
  const float* We2  = (const float*)d_in[11]; const float* be2 = (const float*)d_in[12];
  const float* Ws2  = (const float*)d_in[13]; const float* bs2 = (const float*)d_in[14];
  const float* Wm3  = (const float*)d_in[15]; const float* bm3 = (const float*)d_in[16];
  const float* We3  = (const float*)d_in[17]; const float* be3 = (const float*)d_in[18];
  const float* Ws3  = (const float*)d_in[19]; const float* bs3 = (const float*)d_in[20];
  const float* Wl   = (const float*)d_in[21]; const float* bl  = (const float*)d_in[22];

  // workspace layout (4B units)
  int*   wsi = (int*)d_ws;
  size_t o_cnt = 0;
  size_t o_gc  = o_cnt + (size_t)N;
  size_t o_rs  = o_gc  + 64;
  size_t o_cur = o_rs  + (size_t)N;
  size_t o_adj = o_cur + (size_t)N;        // int2 per edge
  size_t o_eagg= o_adj + (size_t)E * 2;
  size_t o_P   = o_eagg + (size_t)N * 16;  // bf16 [N][64] lives in N*32 ints
  size_t o_G   = o_P   + (size_t)N * 32;
  size_t o_H   = o_G   + (size_t)N * 64;

  int* cnt       = wsi + o_cnt;
  int* gcount    = wsi + o_gc;
  int* row_start = wsi + o_rs;
  int* cursor    = wsi + o_cur;
  int2* adj      = (int2*)(wsi + o_adj);
  float* Eagg    = (float*)(wsi + o_eagg);
  float* P       = (float*)(wsi + o_P);    // holds bf16 data
  float* G       = (float*)(wsi + o_G);
  float* H       = (float*)(wsi + o_H);

  float* out0     = (float*)d_out;                       // [N]
  float* out_feat = (float*)d_out + N;                   // [N][64]
  float* out_cat  = (float*)d_out + (size_t)N * 65;      // [N][65]

  const int gE   = (E + 255) / 256;
  const int gN   = (N + 255) / 256;
  const int gE4  = ((size_t)N * 4 + 255) / 256;
  const int gA   = ((size_t)N * 32 + 255) / 256;
  const int g64  = ((size_t)N * 64 + 255) / 256;
  const int gT   = (N + 63) / 64;

  hipMemsetAsync(cnt, 0, (size_t)(N + 64) * sizeof(int), stream);
  k_hist <<<gE, 256, 0, stream>>>(ei, cnt, E);
  k_alloc<<<gN, 256, 0, stream>>>(cnt, row_start, cursor, gcount, N);
  k_fill <<<gE, 256, 0, stream>>>(ei, cursor, adj, E);
  k_eagg <<<gE4, 256, 0, stream>>>((const float4*)eat, adj, row_start, cnt, (float4*)Eagg, N);

  // ---- layer 1 (Cin=128) ----
  k_dense<<<gT, 256, 0, stream>>>(x, Wm1, 128, nullptr, nullptr, 0,
                                  nullptr, nullptr, nullptr, nullptr, nullptr, 0, 1,
                                  P, nullptr, N);
  k_agg64<<<gA, 256, 0, stream>>>((const ushort2*)P, adj, row_start, cnt, (float2*)G, N);
  k_dense<<<gT, 256, 0, stream>>>(x, Ws1, 128, Eagg, We1, 16,
                                  G, cnt, bm1, be1, bs1, 1, 0,
                                  H, nullptr, N);
  // ---- layer 2 (Cin=64) ----
  k_dense<<<gT, 256, 0, stream>>>(H, Wm2, 64, nullptr, nullptr, 0,
                                  nullptr, nullptr, nullptr, nullptr, nullptr, 0, 1,
                                  P, nullptr, N);
  k_agg64<<<gA, 256, 0, stream>>>((const ushort2*)P, adj, row_start, cnt, (float2*)G, N);
  k_dense<<<gT, 256, 0, stream>>>(H, Ws2, 64, Eagg, We2, 16,
                                  G, cnt, bm2, be2, bs2, 1, 0,
                                  out_feat, out_cat, N);
  // ---- layer 3 (Cin=64) ----
  k_dense<<<gT, 256, 0, stream>>>(out_feat, Wm3, 64, nullptr, nullptr, 0,
                                  nullptr, nullptr, nullptr, nullptr, nullptr, 0, 1,
                                  P, nullptr, N);
  k_agg64<<<gA, 256, 0, stream>>>((const ushort2*)P, adj, row_start, cnt, (float2*)G, N);
  k_dense<<<gT, 256, 0, stream>>>(out_feat, Ws3, 64, Eagg, We3, 16,
                                  G, cnt, bm3, be3, bs3, 1, 0,
                                  H, nullptr, N);

  k_final<<<g64, 256, 0, stream>>>(H, Wl, bl, out0, out_cat, N);
}

// Round 3
// 589.744 us; speedup vs baseline: 1.6255x; 1.1931x over previous
//
#include <hip/hip_runtime.h>
#include <math.h>

// GeneralConvNet: 3x GeneralConv + ELU, then linear->sigmoid.
// per layer: out = ELU( Adj@(x@Wm) + x@Ws + Eagg@We + deg*(bm+be) + bs )
// MFMA bf16 dual-GEMM per layer (A@[Wm|Ws] + Eagg@[0|We] folded as extra K-chunk),
// CSR gather-aggregate in bf16, elementwise combine epilogue.

typedef __attribute__((ext_vector_type(8))) short short8;
typedef __attribute__((ext_vector_type(4))) float f32x4;

static __device__ __forceinline__ float elu_f(float v){ return v > 0.f ? v : expm1f(v); }

static __device__ __forceinline__ unsigned short f2bf_rne(float f){
  unsigned u = __float_as_uint(f);
  u += 0x7FFFu + ((u >> 16) & 1u);
  return (unsigned short)(u >> 16);
}
static __device__ __forceinline__ float bf2f(unsigned short b){
  return __uint_as_float(((unsigned)b) << 16);
}

// ---------- x f32 -> bf16 ----------
__global__ void k_cvt(const float4* __restrict__ in, ushort4* __restrict__ out, long n4){
  long t = (long)blockIdx.x * 256 + threadIdx.x;
  if (t >= n4) return;
  float4 v = in[t];
  ushort4 o; o.x = f2bf_rne(v.x); o.y = f2bf_rne(v.y); o.z = f2bf_rne(v.z); o.w = f2bf_rne(v.w);
  out[t] = o;
}

// ---------- CSR build ----------
__global__ void k_hist(const int* __restrict__ ei, int* __restrict__ cnt, int E){
  int i = blockIdx.x * 256 + threadIdx.x;
  if (i < E) atomicAdd(&cnt[ei[E + i]], 1);
}

__global__ void k_alloc(const int* __restrict__ cnt, int* __restrict__ row_start,
                        int* __restrict__ cursor, int* __restrict__ gcount, int N){
  int i = blockIdx.x * 256 + threadIdx.x;
  int lane = threadIdx.x & 63;
  int c = (i < N) ? cnt[i] : 0;
  int s = c;
  #pragma unroll
  for (int d = 1; d < 64; d <<= 1){
    int t = __shfl_up(s, d);
    if (lane >= d) s += t;
  }
  int total = __shfl(s, 63);
  int base = 0;
  if (lane == 63) base = atomicAdd(gcount, total);
  base = __shfl(base, 63);
  int start = base + s - c;
  if (i < N){ row_start[i] = start; cursor[i] = start; }
}

__global__ void k_fill(const int* __restrict__ ei, int* __restrict__ cursor,
                       int2* __restrict__ adj, int E){
  int e = blockIdx.x * 256 + threadIdx.x;
  if (e < E){
    int d = ei[E + e];
    int pos = atomicAdd(&cursor[d], 1);
    adj[pos] = make_int2(ei[e], e);   // {src, edge_id}
  }
}

// ---------- edge-attr aggregation -> Eagg bf16 [N][32] (upper 16 zero) ----------
__global__ void k_eagg(const float4* __restrict__ eattr4, const int2* __restrict__ adj,
                       const int* __restrict__ row_start, const int* __restrict__ cnt,
                       unsigned short* __restrict__ Eagg, int N){
  int t = blockIdx.x * 256 + threadIdx.x;
  int i = t >> 2, q = t & 3;
  if (i >= N) return;
  int lane = threadIdx.x & 63;
  int gbase = lane & 60;
  int p0 = row_start[i], n = cnt[i];
  float4 s = make_float4(0.f, 0.f, 0.f, 0.f);
  int c = 0;
  for (; c + 4 <= n; c += 4){
    int ereg = adj[p0 + c + q].y;
    int e0 = __shfl(ereg, gbase + 0), e1 = __shfl(ereg, gbase + 1);
    int e2 = __shfl(ereg, gbase + 2), e3 = __shfl(ereg, gbase + 3);
    float4 v0 = eattr4[(long)e0 * 4 + q];
    float4 v1 = eattr4[(long)e1 * 4 + q];
    float4 v2 = eattr4[(long)e2 * 4 + q];
    float4 v3 = eattr4[(long)e3 * 4 + q];
    s.x += v0.x + v1.x + v2.x + v3.x;
    s.y += v0.y + v1.y + v2.y + v3.y;
    s.z += v0.z + v1.z + v2.z + v3.z;
    s.w += v0.w + v1.w + v2.w + v3.w;
  }
  if (c < n){
    int m = n - c;
    int ereg = (q < m) ? adj[p0 + c + q].y : 0;
    for (int p = 0; p < m; ++p){
      int e = __shfl(ereg, gbase + p);
      float4 v = eattr4[(long)e * 4 + q];
      s.x += v.x; s.y += v.y; s.z += v.z; s.w += v.w;
    }
  }
  ushort4 o; o.x = f2bf_rne(s.x); o.y = f2bf_rne(s.y); o.z = f2bf_rne(s.z); o.w = f2bf_rne(s.w);
  *reinterpret_cast<ushort4*>(Eagg + (long)i * 32 + q * 4) = o;
  ushort4 z; z.x = 0; z.y = 0; z.z = 0; z.w = 0;
  *reinterpret_cast<ushort4*>(Eagg + (long)i * 32 + 16 + q * 4) = z;
}

// ---------- 64-dim bf16 gather-aggregate: G[i] = sum_{e: dst=i} P[src(e)] ----------
// 16 lanes/node, bf16x4 per lane, 4-deep unrolled gathers for MLP.
__global__ void k_agg64(const unsigned short* __restrict__ P, const int2* __restrict__ adj,
                        const int* __restrict__ row_start, const int* __restrict__ cnt,
                        float* __restrict__ G, int N){
  int t = blockIdx.x * 256 + threadIdx.x;
  int i = t >> 4, q = t & 15;
  if (i >= N) return;
  int lane = threadIdx.x & 63;
  int gbase = lane & 48;
  int p0 = row_start[i], n = cnt[i];
  float a0 = 0.f, a1 = 0.f, a2 = 0.f, a3 = 0.f;
  for (int c = 0; c < n; c += 16){
    int m = n - c; if (m > 16) m = 16;
    int sreg = (q < m) ? adj[p0 + c + q].x : 0;
    int p = 0;
    for (; p + 4 <= m; p += 4){
      int s0 = __shfl(sreg, gbase + p + 0);
      int s1 = __shfl(sreg, gbase + p + 1);
      int s2 = __shfl(sreg, gbase + p + 2);
      int s3 = __shfl(sreg, gbase + p + 3);
      ushort4 v0 = *reinterpret_cast<const ushort4*>(P + (long)s0 * 64 + q * 4);
      ushort4 v1 = *reinterpret_cast<const ushort4*>(P + (long)s1 * 64 + q * 4);
      ushort4 v2 = *reinterpret_cast<const ushort4*>(P + (long)s2 * 64 + q * 4);
      ushort4 v3 = *reinterpret_cast<const ushort4*>(P + (long)s3 * 64 + q * 4);
      a0 += bf2f(v0.x) + bf2f(v1.x) + bf2f(v2.x) + bf2f(v3.x);
      a1 += bf2f(v0.y) + bf2f(v1.y) + bf2f(v2.y) + bf2f(v3.y);
      a2 += bf2f(v0.z) + bf2f(v1.z) + bf2f(v2.z) + bf2f(v3.z);
      a3 += bf2f(v0.w) + bf2f(v1.w) + bf2f(v2.w) + bf2f(v3.w);
    }
    for (; p < m; ++p){
      int s0 = __shfl(sreg, gbase + p);
      ushort4 v = *reinterpret_cast<const ushort4*>(P + (long)s0 * 64 + q * 4);
      a0 += bf2f(v.x); a1 += bf2f(v.y); a2 += bf2f(v.z); a3 += bf2f(v.w);
    }
  }
  *reinterpret_cast<float4*>(G + (long)i * 64 + q * 4) = make_float4(a0, a1, a2, a3);
}

// ---------- dual MFMA GEMM: [P | S] = A @ [Wm | Ws] + Eagg @ [0 | We] ----------
// block 256 = 4 waves; tile 128 rows x 128 cols; wave (wr,wc) does 64x64.
// cols 0-63 -> P (bf16), cols 64-127 -> S (f32).
__global__ __launch_bounds__(256) void k_dual(
    const unsigned short* __restrict__ A, int K,
    const unsigned short* __restrict__ Eagg,
    const float* __restrict__ Wm, const float* __restrict__ Ws, const float* __restrict__ We,
    unsigned short* __restrict__ P, float* __restrict__ S, int N)
{
  extern __shared__ unsigned short Wt[];   // [128 cols][SW], SW = K+40
  const int SW = K + 40;
  const int tid = threadIdx.x;

  // stage weights (transposed, bf16)
  for (int idx = tid; idx < (K << 7); idx += 256){
    int k = idx >> 7, c = idx & 127;
    float v = (c < 64) ? Wm[k * 64 + c] : Ws[k * 64 + (c - 64)];
    Wt[c * SW + k] = f2bf_rne(v);
  }
  for (int idx = tid; idx < (32 << 7); idx += 256){
    int k2 = idx >> 7, c = idx & 127;
    float v = (c >= 64 && k2 < 16) ? We[k2 * 64 + (c - 64)] : 0.f;
    Wt[c * SW + K + k2] = f2bf_rne(v);
  }
  __syncthreads();

  const int w = tid >> 6, lane = tid & 63;
  const int wr = w & 1, wc = w >> 1;
  const int l15 = lane & 15, lg = lane >> 4;
  const long tile0 = (long)blockIdx.x * 128;

  f32x4 acc[4][4];
  #pragma unroll
  for (int a = 0; a < 4; ++a)
    #pragma unroll
    for (int b = 0; b < 4; ++b)
      acc[a][b] = (f32x4){0.f, 0.f, 0.f, 0.f};

  const int NC = (K >> 5) + 1;
  for (int kc = 0; kc < NC; ++kc){
    const unsigned short* Ap; long astr; int kin;
    if (kc < NC - 1){ Ap = A; astr = K; kin = kc * 32 + lg * 8; }
    else            { Ap = Eagg; astr = 32; kin = lg * 8; }
    short8 af[4], bfv[4];
    #pragma unroll
    for (int rt = 0; rt < 4; ++rt){
      long node = tile0 + wr * 64 + rt * 16 + l15;
      long nn = (node < N) ? node : 0;
      af[rt] = *reinterpret_cast<const short8*>(Ap + nn * astr + kin);
    }
    int kB = kc * 32 + lg * 8;
    #pragma unroll
    for (int ct = 0; ct < 4; ++ct){
      int col = wc * 64 + ct * 16 + l15;
      bfv[ct] = *reinterpret_cast<const short8*>(&Wt[col * SW + kB]);
    }
    #pragma unroll
    for (int rt = 0; rt < 4; ++rt)
      #pragma unroll
      for (int ct = 0; ct < 4; ++ct)
        acc[rt][ct] = __builtin_amdgcn_mfma_f32_16x16x32_bf16(af[rt], bfv[ct], acc[rt][ct], 0, 0, 0);
  }

  // epilogue: C layout col = lane&15, row = (lane>>4)*4 + reg
  if (wc == 0){
    #pragma unroll
    for (int rt = 0; rt < 4; ++rt){
      #pragma unroll
      for (int r = 0; r < 4; ++r){
        long node = tile0 + wr * 64 + rt * 16 + lg * 4 + r;
        if (node < N){
          #pragma unroll
          for (int ct = 0; ct < 4; ++ct)
            P[node * 64 + ct * 16 + l15] = f2bf_rne(acc[rt][ct][r]);
        }
      }
    }
  } else {
    #pragma unroll
    for (int rt = 0; rt < 4; ++rt){
      #pragma unroll
      for (int r = 0; r < 4; ++r){
        long node = tile0 + wr * 64 + rt * 16 + lg * 4 + r;
        if (node < N){
          #pragma unroll
          for (int ct = 0; ct < 4; ++ct)
            S[node * 64 + ct * 16 + l15] = acc[rt][ct][r];
        }
      }
    }
  }
}

// ---------- combine: out = ELU(S + G + deg*(bm+be) + bs); optional outputs ----------
__global__ void k_comb(const float* __restrict__ S, const float* __restrict__ G,
                       const int* __restrict__ cnt,
                       const float* __restrict__ bm, const float* __restrict__ be,
                       const float* __restrict__ bs,
                       float* __restrict__ outF, float* __restrict__ outCat,
                       unsigned short* __restrict__ outH,
                       const float* __restrict__ Wl, const float* __restrict__ bl,
                       float* __restrict__ out0, int N)
{
  int t = blockIdx.x * 256 + threadIdx.x;
  int i = t >> 4, q = t & 15;
  if (i >= N) return;
  float4 s = *reinterpret_cast<const float4*>(S + (long)i * 64 + q * 4);
  float4 g = *reinterpret_cast<const float4*>(G + (long)i * 64 + q * 4);
  float deg = (float)cnt[i];
  float4 vb = *reinterpret_cast<const float4*>(bm + q * 4);
  float4 ve = *reinterpret_cast<const float4*>(be + q * 4);
  float4 vs = *reinterpret_cast<const float4*>(bs + q * 4);
  float v0 = elu_f(s.x + g.x + deg * (vb.x + ve.x) + vs.x);
  float v1 = elu_f(s.y + g.y + deg * (vb.y + ve.y) + vs.y);
  float v2 = elu_f(s.z + g.z + deg * (vb.z + ve.z) + vs.z);
  float v3 = elu_f(s.w + g.w + deg * (vb.w + ve.w) + vs.w);
  if (outF)
    *reinterpret_cast<float4*>(outF + (long)i * 64 + q * 4) = make_float4(v0, v1, v2, v3);
  if (outCat && !Wl){
    long b = (long)i * 65 + q * 4;
    outCat[b + 0] = v0; outCat[b + 1] = v1; outCat[b + 2] = v2; outCat[b + 3] = v3;
  }
  if (outH){
    ushort4 o; o.x = f2bf_rne(v0); o.y = f2bf_rne(v1); o.z = f2bf_rne(v2); o.w = f2bf_rne(v3);
    *reinterpret_cast<ushort4*>(outH + (long)i * 64 + q * 4) = o;
  }
  if (Wl){
    float4 wl = *reinterpret_cast<const float4*>(Wl + q * 4);
    float d = v0 * wl.x + v1 * wl.y + v2 * wl.z + v3 * wl.w;
    #pragma unroll
    for (int o = 8; o; o >>= 1) d += __shfl_xor(d, o);
    if (q == 0){
      float logit = d + bl[0];
      out0[i] = 1.f / (1.f + expf(-logit));
      outCat[(long)i * 65 + 64] = logit;
    }
  }
}

extern "C" void kernel_launch(void* const* d_in, const int* in_sizes, int n_in,
                              void* d_out, int out_size, void* d_ws, size_t ws_size,
                              hipStream_t stream) {
  const int N = in_sizes[0] / 128;
  const int E = in_sizes[1] / 2;

  const float* x    = (const float*)d_in[0];
  const int*   ei   = (const int*)  d_in[1];
  const float* eat  = (const float*)d_in[2];
  const float* Wm1  = (const float*)d_in[3];  const float* bm1 = (const float*)d_in[4];
  const float* We1  = (const float*)d_in[5];  const float* be1 = (const float*)d_in[6];
  const float* Ws1  = (const float*)d_in[7];  const float* bs1 = (const float*)d_in[8];
  const float* Wm2  = (const float*)d_in[9];  const float* bm2 = (const float*)d_in[10];
  const float* We2  = (const float*)d_in[11]; const float* be2 = (const float*)d_in[12];
  const float* Ws2  = (const float*)d_in[13]; const float* bs2 = (const float*)d_in[14];
  const float* Wm3  = (const float*)d_in[15]; const float* bm3 = (const float*)d_in[16];
  const float* We3  = (const float*)d_in[17]; const float* be3 = (const float*)d_in[18];
  const float* Ws3  = (const float*)d_in[19]; const float* bs3 = (const float*)d_in[20];
  const float* Wl   = (const float*)d_in[21]; const float* bl  = (const float*)d_in[22];

  // workspace layout (4B units)
  int* wsi = (int*)d_ws;
  size_t o_cnt  = 0;                         // N
  size_t o_gc   = o_cnt  + (size_t)N;        // 64
  size_t o_rs   = o_gc   + 64;               // N
  size_t o_cur  = o_rs   + (size_t)N;        // N
  size_t o_adj  = o_cur  + (size_t)N;        // 2E (int2)
  size_t o_eagg = o_adj  + (size_t)E * 2;    // 16N  (bf16 [N][32])
  size_t o_P    = o_eagg + (size_t)N * 16;   // 32N  (bf16 [N][64])
  size_t o_S    = o_P    + (size_t)N * 32;   // 64N  (f32 [N][64])
  size_t o_xG   = o_S    + (size_t)N * 64;   // 64N  (x_bf [N][128] bf16; later G f32 [N][64])
  size_t o_Hb   = o_xG   + (size_t)N * 64;   // 32N  (bf16 [N][64])

  int* cnt       = wsi + o_cnt;
  int* gcount    = wsi + o_gc;
  int* row_start = wsi + o_rs;
  int* cursor    = wsi + o_cur;
  int2* adj      = (int2*)(wsi + o_adj);
  unsigned short* Eagg = (unsigned short*)(wsi + o_eagg);
  unsigned short* P    = (unsigned short*)(wsi + o_P);
  float* S       = (float*)(wsi + o_S);
  unsigned short* x_bf = (unsigned short*)(wsi + o_xG);
  float* G       = (float*)(wsi + o_xG);     // aliases x_bf (x_bf dead after dual1)
  unsigned short* Hb   = (unsigned short*)(wsi + o_Hb);

  float* out0     = (float*)d_out;                       // [N]
  float* out_feat = (float*)d_out + N;                   // [N][64]
  float* out_cat  = (float*)d_out + (size_t)N * 65;      // [N][65]

  const int gE   = (E + 255) / 256;
  const int gN   = (N + 255) / 256;
  const long n4x = (long)N * 32;
  const int gCVT = (int)((n4x + 255) / 256);
  const int gEA  = ((size_t)N * 4 + 255) / 256;
  const int gAGG = ((size_t)N * 16 + 255) / 256;
  const int gT   = (N + 127) / 128;

  hipMemsetAsync(cnt, 0, (size_t)(N + 64) * sizeof(int), stream);
  k_cvt  <<<gCVT, 256, 0, stream>>>((const float4*)x, (ushort4*)x_bf, n4x);
  k_hist <<<gE, 256, 0, stream>>>(ei, cnt, E);
  k_alloc<<<gN, 256, 0, stream>>>(cnt, row_start, cursor, gcount, N);
  k_fill <<<gE, 256, 0, stream>>>(ei, cursor, adj, E);
  k_eagg <<<gEA, 256, 0, stream>>>((const float4*)eat, adj, row_start, cnt, Eagg, N);

  const size_t lds128 = 128 * (128 + 40) * sizeof(unsigned short);
  const size_t lds64  = 128 * (64 + 40) * sizeof(unsigned short);

  // ---- layer 1 (K=128) ----
  k_dual<<<gT, 256, lds128, stream>>>(x_bf, 128, Eagg, Wm1, Ws1, We1, P, S, N);
  k_agg64<<<gAGG, 256, 0, stream>>>(P, adj, row_start, cnt, G, N);
  k_comb<<<gAGG, 256, 0, stream>>>(S, G, cnt, bm1, be1, bs1,
                                   nullptr, nullptr, Hb, nullptr, nullptr, nullptr, N);
  // ---- layer 2 (K=64) ----
  k_dual<<<gT, 256, lds64, stream>>>(Hb, 64, Eagg, Wm2, Ws2, We2, P, S, N);
  k_agg64<<<gAGG, 256, 0, stream>>>(P, adj, row_start, cnt, G, N);
  k_comb<<<gAGG, 256, 0, stream>>>(S, G, cnt, bm2, be2, bs2,
                                   out_feat, out_cat, Hb, nullptr, nullptr, nullptr, N);
  // ---- layer 3 (K=64) ----
  k_dual<<<gT, 256, lds64, stream>>>(Hb, 64, Eagg, Wm3, Ws3, We3, P, S, N);
  k_agg64<<<gAGG, 256, 0, stream>>>(P, adj, row_start, cnt, G, N);
  k_comb<<<gAGG, 256, 0, stream>>>(S, G, cnt, bm3, be3, bs3,
                                   nullptr, out_cat, nullptr, Wl, bl, out0, N);
}